// Round 3
// baseline (78.637 us; speedup 1.0000x reference)
//
#include <hip/hip_runtime.h>
#include <math.h>

#define BATCH 32
#define CH    256
#define HH    64
#define WW    64
#define HW    (HH * WW)                  // 4096
#define NPIX  (BATCH * HW)               // 131072
#define PG    (NPIX / 4)                 // 32768 float4 pixel-groups
#define NTOT  ((size_t)BATCH * CH * HW)  // 33554432
#define NCHUNK 8
#define CCHUNK (CH / NCHUNK)             // 32

typedef float floatx4 __attribute__((ext_vector_type(4)));

// Kernel 1: partial channel-wise sum + max over a 32-channel chunk,
// float4-vectorized over pixels. 1024 blocks x 256 threads.
__global__ __launch_bounds__(256) void sa_pool_partial_kernel(
    const float* __restrict__ x,
    float4* __restrict__ pSum, float4* __restrict__ pMax) {
    int t = blockIdx.x * blockDim.x + threadIdx.x;      // [0, PG*NCHUNK)
    int pg    = t & (PG - 1);                           // pixel group
    int chunk = t >> 15;                                // channel chunk
    int b   = pg >> 10;                                 // PG per batch = 1024
    int hwg = pg & 1023;
    const float4* p = reinterpret_cast<const float4*>(
        x + (size_t)b * CH * HW + (size_t)chunk * CCHUNK * HW) + hwg;
    float4 s = make_float4(0.f, 0.f, 0.f, 0.f);
    float4 m = make_float4(-INFINITY, -INFINITY, -INFINITY, -INFINITY);
#pragma unroll 8
    for (int c = 0; c < CCHUNK; ++c) {
        float4 v = p[c * (HW / 4)];
        s.x += v.x; s.y += v.y; s.z += v.z; s.w += v.w;
        m.x = fmaxf(m.x, v.x); m.y = fmaxf(m.y, v.y);
        m.z = fmaxf(m.z, v.z); m.w = fmaxf(m.w, v.w);
    }
    pSum[chunk * PG + pg] = s;
    pMax[chunk * PG + pg] = m;
}

// Kernel 2: combine partials -> pooled = mean + max. 128 blocks x 256.
__global__ __launch_bounds__(256) void sa_pool_combine_kernel(
    const float4* __restrict__ pSum, const float4* __restrict__ pMax,
    float4* __restrict__ pooled) {
    int pg = blockIdx.x * blockDim.x + threadIdx.x;
    if (pg >= PG) return;
    float4 s = make_float4(0.f, 0.f, 0.f, 0.f);
    float4 m = make_float4(-INFINITY, -INFINITY, -INFINITY, -INFINITY);
#pragma unroll
    for (int c = 0; c < NCHUNK; ++c) {
        float4 sv = pSum[c * PG + pg];
        float4 mv = pMax[c * PG + pg];
        s.x += sv.x; s.y += sv.y; s.z += sv.z; s.w += sv.w;
        m.x = fmaxf(m.x, mv.x); m.y = fmaxf(m.y, mv.y);
        m.z = fmaxf(m.z, mv.z); m.w = fmaxf(m.w, mv.w);
    }
    const float inv = 1.0f / (float)CH;
    float4 o;
    o.x = s.x * inv + m.x; o.y = s.y * inv + m.y;
    o.z = s.z * inv + m.z; o.w = s.w * inv + m.w;
    pooled[pg] = o;
}

// Kernel 3: 7x7 SAME conv (1->1 ch) + bias + sigmoid -> attn [B, H, W]
__global__ __launch_bounds__(256) void sa_conv_kernel(
    const float* __restrict__ pooled, const float* __restrict__ wgt,
    const float* __restrict__ bias, float* __restrict__ attn) {
    int idx = blockIdx.x * blockDim.x + threadIdx.x;
    if (idx >= NPIX) return;
    int b  = idx >> 12;
    int hw = idx & 4095;
    int h  = hw >> 6;
    int w  = hw & 63;
    const float* pb = pooled + b * HW;
    float acc = bias[0];
#pragma unroll
    for (int kh = 0; kh < 7; ++kh) {
        int hh2 = h + kh - 3;
        if (hh2 < 0 || hh2 >= HH) continue;
#pragma unroll
        for (int kw = 0; kw < 7; ++kw) {
            int ww2 = w + kw - 3;
            if (ww2 < 0 || ww2 >= WW) continue;
            acc += pb[hh2 * WW + ww2] * wgt[kh * 7 + kw];
        }
    }
    attn[idx] = 1.0f / (1.0f + __expf(-acc));
}

// Kernel 4: out = x * attn (broadcast over channels), float4 + NT stores
__global__ __launch_bounds__(256) void sa_mul_kernel(
    const float* __restrict__ x, const float* __restrict__ attn,
    float* __restrict__ out) {
    size_t i = ((size_t)blockIdx.x * blockDim.x + threadIdx.x) * 4;
    if (i >= NTOT) return;
    size_t bc = i >> 12;         // b*CH + c
    int hw    = (int)(i & 4095);
    int b     = (int)(bc >> 8);  // / 256
    float4 xv = *reinterpret_cast<const float4*>(x + i);
    float4 av = *reinterpret_cast<const float4*>(attn + (size_t)b * HW + hw);
    floatx4 o;
    o.x = xv.x * av.x;
    o.y = xv.y * av.y;
    o.z = xv.z * av.z;
    o.w = xv.w * av.w;
    __builtin_nontemporal_store(o, reinterpret_cast<floatx4*>(out + i));
}

extern "C" void kernel_launch(void* const* d_in, const int* in_sizes, int n_in,
                              void* d_out, int out_size, void* d_ws, size_t ws_size,
                              hipStream_t stream) {
    const float* x    = (const float*)d_in[0];
    const float* wgt  = (const float*)d_in[1];
    const float* bias = (const float*)d_in[2];
    float* out = (float*)d_out;

    // ws layout (floats): pooled [NPIX], attn [NPIX], pSum [NCHUNK*PG*4],
    // pMax [NCHUNK*PG*4]  -> total ~9 MiB (ws is ~512 MiB)
    float*  pooled = (float*)d_ws;
    float*  attn   = pooled + NPIX;
    float4* pSum   = reinterpret_cast<float4*>(attn + NPIX);
    float4* pMax   = pSum + (size_t)NCHUNK * PG;

    {
        dim3 block(256);
        dim3 grid((PG * NCHUNK) / 256);          // 1024 blocks
        sa_pool_partial_kernel<<<grid, block, 0, stream>>>(x, pSum, pMax);
    }
    {
        dim3 block(256);
        dim3 grid((PG + 255) / 256);             // 128 blocks
        sa_pool_combine_kernel<<<grid, block, 0, stream>>>(
            pSum, pMax, reinterpret_cast<float4*>(pooled));
    }
    {
        dim3 block(256);
        dim3 grid((NPIX + 255) / 256);           // 512 blocks
        sa_conv_kernel<<<grid, block, 0, stream>>>(pooled, wgt, bias, attn);
    }
    {
        dim3 block(256);
        dim3 grid((unsigned)((NTOT / 4 + 255) / 256));  // 32768 blocks
        sa_mul_kernel<<<grid, block, 0, stream>>>(x, attn, out);
    }
}